// Round 5
// baseline (1269.598 us; speedup 1.0000x reference)
//
#include <hip/hip_runtime.h>
#include <math.h>

typedef __bf16 bf16x8 __attribute__((ext_vector_type(8)));
typedef float f32x4 __attribute__((ext_vector_type(4)));

#define DDIM 1024
#define HDIM 4096
#define NE 8
#define TT 4096
#define CAP 8192

static const size_t OFF_CTRL   = 0;                                      // 256 B
static const size_t OFF_ROWMAP = 256;                                    // CAP*4
static const size_t OFF_WROW   = OFF_ROWMAP + (size_t)CAP * 4;           // CAP*4
static const size_t OFF_TOKE   = OFF_WROW + (size_t)CAP * 4;             // TT*2*4
static const size_t OFF_TOKW   = OFF_TOKE + (size_t)TT * 2 * 4;          // TT*2*4
static const size_t OFF_XB     = OFF_TOKW + (size_t)TT * 2 * 4;          // TT*D bf16
static const size_t OFF_W1T    = OFF_XB + (size_t)TT * DDIM * 2;         // E*H*D bf16
static const size_t OFF_W2T    = OFF_W1T + (size_t)NE * HDIM * DDIM * 2; // E*D*H bf16
static const size_t OFF_H      = OFF_W2T + (size_t)NE * DDIM * HDIM * 2; // CAP*H bf16
static const size_t WS_NEED    = OFF_H + (size_t)CAP * HDIM * 2;         // ~203 MiB

__device__ __forceinline__ unsigned short f2bf(float f) {
  unsigned int u = __builtin_bit_cast(unsigned int, f);
  u = (u + 0x7FFFu + ((u >> 16) & 1u)) >> 16;
  return (unsigned short)u;
}

__device__ __forceinline__ void async16(void* lds, const void* g) {
  __builtin_amdgcn_global_load_lds(
      (__attribute__((address_space(1))) void*)g,
      (__attribute__((address_space(3))) void*)lds, 16, 0, 0);
}

__device__ __forceinline__ float gelu_exact(float v) {
  return 0.5f * v * (1.0f + erff(v * 0.70710678118654752f));
}

// ---------------- router ----------------
__global__ __launch_bounds__(256) void router_k(
    const float* __restrict__ x, const float* __restrict__ Wr, const float* __restrict__ br,
    unsigned short* __restrict__ xb, int* __restrict__ ctrl,
    int* __restrict__ toke, float* __restrict__ tokw) {
  int tid = threadIdx.x, lane = tid & 63, wid = tid >> 6;
  int t = blockIdx.x * 4 + wid;
  const float* xr = x + (size_t)t * DDIM;
  float acc[NE];
#pragma unroll
  for (int e = 0; e < NE; ++e) acc[e] = 0.f;
#pragma unroll
  for (int it = 0; it < DDIM / 64; ++it) {
    int d = lane + it * 64;
    float xv = xr[d];
    xb[(size_t)t * DDIM + d] = f2bf(xv);
    const float4* w4 = (const float4*)(Wr + (size_t)d * NE);
    float4 wa = w4[0], wb = w4[1];
    acc[0] += xv * wa.x; acc[1] += xv * wa.y; acc[2] += xv * wa.z; acc[3] += xv * wa.w;
    acc[4] += xv * wb.x; acc[5] += xv * wb.y; acc[6] += xv * wb.z; acc[7] += xv * wb.w;
  }
#pragma unroll
  for (int e = 0; e < NE; ++e) {
#pragma unroll
    for (int s = 32; s > 0; s >>= 1) acc[e] += __shfl_xor(acc[e], s, 64);
  }
  if (lane == 0) {
    float l[NE];
#pragma unroll
    for (int e = 0; e < NE; ++e) l[e] = acc[e] + br[e];
    int i0 = 0; float m0 = l[0];
#pragma unroll
    for (int e = 1; e < NE; ++e) if (l[e] > m0) { m0 = l[e]; i0 = e; }
    int i1 = -1; float m1 = -3.4e38f;
#pragma unroll
    for (int e = 0; e < NE; ++e) if (e != i0 && l[e] > m1) { m1 = l[e]; i1 = e; }
    float e1 = expf(m1 - m0);
    float s = 1.f + e1;
    toke[2 * t] = i0;  toke[2 * t + 1] = i1;
    tokw[2 * t] = 1.f / s;  tokw[2 * t + 1] = e1 / s;
    atomicAdd(&ctrl[i0], 1);
    atomicAdd(&ctrl[i1], 1);
  }
}

__global__ void scan_k(int* ctrl) {
  if (threadIdx.x == 0) {
    int off = 0;
    for (int e = 0; e < NE; ++e) {
      ctrl[8 + e] = off;
      ctrl[20 + e] = off;
      off += ctrl[e];
    }
    ctrl[16] = off;
  }
}

__global__ __launch_bounds__(256) void assign_k(
    const int* __restrict__ toke, const float* __restrict__ tokw, int* ctrl,
    int* __restrict__ rowmap, float* __restrict__ wrow) {
  int t = blockIdx.x * 256 + threadIdx.x;
#pragma unroll
  for (int k = 0; k < 2; ++k) {
    int e = toke[2 * t + k];
    int r = atomicAdd(&ctrl[20 + e], 1);
    rowmap[r] = t;
    wrow[r] = tokw[2 * t + k];
  }
}

// ---------------- fp32 -> bf16 transpose convert: src[e][K_][N_] -> dst[e][N_][K_] ----------------
__global__ __launch_bounds__(256) void convT_k(
    const float* __restrict__ src, unsigned short* __restrict__ dst, int K_, int N_) {
  __shared__ unsigned int lds32[64][33];
  int e = blockIdx.z;
  int kb = blockIdx.y << 6, nb = blockIdx.x << 6;
  int t = threadIdx.x;
  const float* s = src + (size_t)e * K_ * N_ + (size_t)kb * N_ + nb;
  int n0 = (t & 15) << 2;
#pragma unroll
  for (int i = 0; i < 2; ++i) {
    int k2 = (i << 4) + (t >> 4);
    float4 a = *(const float4*)(s + (size_t)(2 * k2) * N_ + n0);
    float4 b = *(const float4*)(s + (size_t)(2 * k2 + 1) * N_ + n0);
    lds32[n0 + 0][k2] = (unsigned)f2bf(a.x) | ((unsigned)f2bf(b.x) << 16);
    lds32[n0 + 1][k2] = (unsigned)f2bf(a.y) | ((unsigned)f2bf(b.y) << 16);
    lds32[n0 + 2][k2] = (unsigned)f2bf(a.z) | ((unsigned)f2bf(b.z) << 16);
    lds32[n0 + 3][k2] = (unsigned)f2bf(a.w) | ((unsigned)f2bf(b.w) << 16);
  }
  __syncthreads();
  unsigned short* dp = dst + (size_t)e * (size_t)N_ * K_ + (size_t)nb * K_ + kb;
  int n = t >> 2, c = t & 3;
  uint4 v0, v1;
  v0.x = lds32[n][(c << 2) + 0]; v0.y = lds32[n][(c << 2) + 1];
  v0.z = lds32[n][(c << 2) + 2]; v0.w = lds32[n][(c << 2) + 3];
  int c4 = (c + 4) << 2;
  v1.x = lds32[n][c4 + 0]; v1.y = lds32[n][c4 + 1];
  v1.z = lds32[n][c4 + 2]; v1.w = lds32[n][c4 + 3];
  *(uint4*)(dp + (size_t)n * K_ + (c << 3)) = v0;
  *(uint4*)(dp + (size_t)n * K_ + ((c + 4) << 3)) = v1;
}

// ---------------- grouped GEMM: 128x128 tile, 4 waves, dbuf minimal-2ph, swizzled LDS ----------------
// Swizzle: 8-elem k-chunk index XOR'd with (row>>1)&7; applied on the global source
// (inverse = same involution) and on the ds_read offset; gload_lds dest stays linear (rule 21).
// DOGELU: outb[row][n] = bf16(gelu(acc + bias)).  else: atomicAdd(out[token[row]][n], wrow[row]*(acc+bias)).
template <int KTOT, int NTOT, bool GATHER, bool DOGELU>
__global__ __launch_bounds__(256) void gemm_k(
    const unsigned short* __restrict__ A, const unsigned short* __restrict__ Bt,
    const int* __restrict__ ctrl, const int* __restrict__ rowmap,
    const float* __restrict__ wrow, const float* __restrict__ bias,
    unsigned short* __restrict__ outb, float* __restrict__ outf) {
  __shared__ __align__(16) unsigned short AL[2][128 * 64];
  __shared__ __align__(16) unsigned short BL[2][128 * 64];
  int e = blockIdx.z;
  int off0 = ctrl[8 + e], off1 = ctrl[8 + e + 1];
  int row0 = off0 + (blockIdx.x << 7);
  if (row0 >= off1) return;
  int col0 = blockIdx.y << 7;
  int tid = threadIdx.x, lane = tid & 63, wid = tid >> 6;
  int wr = wid >> 1, wc = wid & 1;

  const unsigned short* As[4];
  const unsigned short* Bs[4];
#pragma unroll
  for (int c = 0; c < 4; ++c) {
    int rl = (c << 5) + (tid >> 3);                       // dest row 0..127
    int k0 = (((tid & 7) ^ ((rl >> 1) & 7)) << 3);        // inverse-swizzled source chunk
    int ar = row0 + rl; if (ar > off1 - 1) ar = off1 - 1;
    size_t arow = GATHER ? (size_t)rowmap[ar] : (size_t)ar;
    As[c] = A + arow * KTOT + k0;
    Bs[c] = Bt + ((size_t)e * NTOT + col0 + rl) * KTOT + k0;
  }

  // fragment offsets (element index into 128x64 tile), [frag][kk-half], swizzled
  int offA[4][2], offB[4][2];
#pragma unroll
  for (int m = 0; m < 4; ++m) {
    int r = (wr << 6) + (m << 4) + (lane & 15);
#pragma unroll
    for (int h = 0; h < 2; ++h)
      offA[m][h] = (r << 6) + ((((h << 2) + (lane >> 4)) ^ ((r >> 1) & 7)) << 3);
  }
#pragma unroll
  for (int n = 0; n < 4; ++n) {
    int r = (wc << 6) + (n << 4) + (lane & 15);
#pragma unroll
    for (int h = 0; h < 2; ++h)
      offB[n][h] = (r << 6) + ((((h << 2) + (lane >> 4)) ^ ((r >> 1) & 7)) << 3);
  }

  f32x4 acc[4][4];
#pragma unroll
  for (int m = 0; m < 4; ++m)
#pragma unroll
    for (int n = 0; n < 4; ++n) acc[m][n] = (f32x4){0.f, 0.f, 0.f, 0.f};

#define STG(b, kg)                                                             \
  {                                                                            \
    _Pragma("unroll") for (int c = 0; c < 4; ++c) {                            \
      async16((char*)AL[b] + (((c << 8) + (wid << 6)) << 4), As[c] + (kg));    \
      async16((char*)BL[b] + (((c << 8) + (wid << 6)) << 4), Bs[c] + (kg));    \
    }                                                                          \
  }

  STG(0, 0);
  __syncthreads();
  int cur = 0;
  const int NT = KTOT / 64;
  for (int t = 0; t < NT; ++t) {
    if (t + 1 < NT) STG(cur ^ 1, (t + 1) * 64);   // prefetch next tile first
#pragma unroll
    for (int h = 0; h < 2; ++h) {
      bf16x8 af[4], bfr[4];
#pragma unroll
      for (int m = 0; m < 4; ++m) af[m] = *(const bf16x8*)&AL[cur][offA[m][h]];
#pragma unroll
      for (int n = 0; n < 4; ++n) bfr[n] = *(const bf16x8*)&BL[cur][offB[n][h]];
#pragma unroll
      for (int m = 0; m < 4; ++m)
#pragma unroll
        for (int n = 0; n < 4; ++n)
          acc[m][n] = __builtin_amdgcn_mfma_f32_16x16x32_bf16(af[m], bfr[n], acc[m][n], 0, 0, 0);
    }
    __syncthreads();   // drains prefetch (vmcnt0) + WAR barrier
    cur ^= 1;
  }
#undef STG

  int r_b = (lane >> 4) << 2;
  int c_b = lane & 15;
  if (DOGELU) {
#pragma unroll
    for (int n = 0; n < 4; ++n) {
      int col = col0 + (wc << 6) + (n << 4) + c_b;
      float bv = bias[e * NTOT + col];
#pragma unroll
      for (int m = 0; m < 4; ++m) {
#pragma unroll
        for (int r = 0; r < 4; ++r) {
          int row = row0 + (wr << 6) + (m << 4) + r_b + r;
          if (row < off1)
            outb[(size_t)row * NTOT + col] = f2bf(gelu_exact(acc[m][n][r] + bv));
        }
      }
    }
  } else {
    float bv[4];
#pragma unroll
    for (int n = 0; n < 4; ++n) bv[n] = bias[e * NTOT + col0 + (wc << 6) + (n << 4) + c_b];
#pragma unroll
    for (int m = 0; m < 4; ++m) {
#pragma unroll
      for (int r = 0; r < 4; ++r) {
        int row = row0 + (wr << 6) + (m << 4) + r_b + r;
        if (row < off1) {
          int tk = rowmap[row];
          float w = wrow[row];
#pragma unroll
          for (int n = 0; n < 4; ++n) {
            int col = col0 + (wc << 6) + (n << 4) + c_b;
            atomicAdd(&outf[(size_t)tk * NTOT + col], w * (acc[m][n][r] + bv[n]));
          }
        }
      }
    }
  }
}

extern "C" void kernel_launch(void* const* d_in, const int* in_sizes, int n_in,
                              void* d_out, int out_size, void* d_ws, size_t ws_size,
                              hipStream_t stream) {
  const float* x  = (const float*)d_in[0];
  const float* W1 = (const float*)d_in[1];
  const float* b1 = (const float*)d_in[2];
  const float* W2 = (const float*)d_in[3];
  const float* b2 = (const float*)d_in[4];
  const float* Wr = (const float*)d_in[5];
  const float* br = (const float*)d_in[6];
  float* out = (float*)d_out;

  if (ws_size < WS_NEED) return;

  char* ws = (char*)d_ws;
  int* ctrl            = (int*)(ws + OFF_CTRL);
  int* rowmap          = (int*)(ws + OFF_ROWMAP);
  float* wrow          = (float*)(ws + OFF_WROW);
  int* toke            = (int*)(ws + OFF_TOKE);
  float* tokw          = (float*)(ws + OFF_TOKW);
  unsigned short* xb   = (unsigned short*)(ws + OFF_XB);
  unsigned short* W1T  = (unsigned short*)(ws + OFF_W1T);
  unsigned short* W2T  = (unsigned short*)(ws + OFF_W2T);
  unsigned short* hbuf = (unsigned short*)(ws + OFF_H);

  hipMemsetAsync(ws, 0, 256, stream);                              // ctrl
  hipMemsetAsync(out, 0, (size_t)out_size * 4, stream);            // atomic target

  router_k<<<TT / 4, 256, 0, stream>>>(x, Wr, br, xb, ctrl, toke, tokw);
  scan_k<<<1, 64, 0, stream>>>(ctrl);
  assign_k<<<TT / 256, 256, 0, stream>>>(toke, tokw, ctrl, rowmap, wrow);

  convT_k<<<dim3(HDIM / 64, DDIM / 64, NE), 256, 0, stream>>>(W1, W1T, DDIM, HDIM);
  convT_k<<<dim3(DDIM / 64, HDIM / 64, NE), 256, 0, stream>>>(W2, W2T, HDIM, DDIM);

  // GEMM1: h = gelu(x_rows @ W1[e] + b1)  M=rows(e) (<=4096=TT worst case), N=4096, K=1024
  gemm_k<DDIM, HDIM, true, true><<<dim3(32, HDIM / 128, NE), 256, 0, stream>>>(
      xb, W1T, ctrl, rowmap, wrow, b1, hbuf, nullptr);
  // GEMM2: out[token] += w * (h @ W2[e] + b2)  N=1024, K=4096, fused weighted scatter
  gemm_k<HDIM, DDIM, false, false><<<dim3(32, DDIM / 128, NE), 256, 0, stream>>>(
      hbuf, W2T, ctrl, rowmap, wrow, b2, nullptr, out);
}

// Round 6
// 495.721 us; speedup vs baseline: 2.5611x; 2.5611x over previous
//
#include <hip/hip_runtime.h>
#include <math.h>

typedef __bf16 bf16x8 __attribute__((ext_vector_type(8)));
typedef float f32x4 __attribute__((ext_vector_type(4)));

#define DDIM 1024
#define HDIM 4096
#define NE 8
#define TT 4096
#define CAP 8192

static const size_t OFF_CTRL   = 0;                                      // 256 B
static const size_t OFF_ROWMAP = 256;                                    // CAP*4
static const size_t OFF_WROW   = OFF_ROWMAP + (size_t)CAP * 4;           // CAP*4
static const size_t OFF_ROWPOS = OFF_WROW + (size_t)CAP * 4;             // TT*2*4
static const size_t OFF_TOKE   = OFF_ROWPOS + (size_t)TT * 2 * 4;
static const size_t OFF_TOKW   = OFF_TOKE + (size_t)TT * 2 * 4;
static const size_t OFF_XB     = OFF_TOKW + (size_t)TT * 2 * 4;          // TT*D bf16
static const size_t OFF_W1T    = OFF_XB + (size_t)TT * DDIM * 2;         // E*H*D bf16; reused as pout2 after GEMM1
static const size_t OFF_W2T    = OFF_W1T + (size_t)NE * HDIM * DDIM * 2; // E*D*H bf16
static const size_t OFF_H      = OFF_W2T + (size_t)NE * DDIM * HDIM * 2; // CAP*H bf16
static const size_t OFF_PO     = OFF_H + (size_t)CAP * HDIM * 2;         // CAP*D f32
static const size_t WS_NEED    = OFF_PO + (size_t)CAP * DDIM * 4;

__device__ __forceinline__ unsigned short f2bf(float f) {
  unsigned int u = __builtin_bit_cast(unsigned int, f);
  u = (u + 0x7FFFu + ((u >> 16) & 1u)) >> 16;
  return (unsigned short)u;
}

__device__ __forceinline__ void async16(void* lds, const void* g) {
  __builtin_amdgcn_global_load_lds(
      (__attribute__((address_space(1))) void*)g,
      (__attribute__((address_space(3))) void*)lds, 16, 0, 0);
}

__device__ __forceinline__ float gelu_exact(float v) {
  return 0.5f * v * (1.0f + erff(v * 0.70710678118654752f));
}

// ---------------- router ----------------
__global__ __launch_bounds__(256) void router_k(
    const float* __restrict__ x, const float* __restrict__ Wr, const float* __restrict__ br,
    unsigned short* __restrict__ xb, int* __restrict__ ctrl,
    int* __restrict__ toke, float* __restrict__ tokw) {
  int tid = threadIdx.x, lane = tid & 63, wid = tid >> 6;
  int t = blockIdx.x * 4 + wid;
  const float* xr = x + (size_t)t * DDIM;
  float acc[NE];
#pragma unroll
  for (int e = 0; e < NE; ++e) acc[e] = 0.f;
#pragma unroll
  for (int it = 0; it < DDIM / 64; ++it) {
    int d = lane + it * 64;
    float xv = xr[d];
    xb[(size_t)t * DDIM + d] = f2bf(xv);
    const float4* w4 = (const float4*)(Wr + (size_t)d * NE);
    float4 wa = w4[0], wb = w4[1];
    acc[0] += xv * wa.x; acc[1] += xv * wa.y; acc[2] += xv * wa.z; acc[3] += xv * wa.w;
    acc[4] += xv * wb.x; acc[5] += xv * wb.y; acc[6] += xv * wb.z; acc[7] += xv * wb.w;
  }
#pragma unroll
  for (int e = 0; e < NE; ++e) {
#pragma unroll
    for (int s = 32; s > 0; s >>= 1) acc[e] += __shfl_xor(acc[e], s, 64);
  }
  if (lane == 0) {
    float l[NE];
#pragma unroll
    for (int e = 0; e < NE; ++e) l[e] = acc[e] + br[e];
    int i0 = 0; float m0 = l[0];
#pragma unroll
    for (int e = 1; e < NE; ++e) if (l[e] > m0) { m0 = l[e]; i0 = e; }
    int i1 = -1; float m1 = -3.4e38f;
#pragma unroll
    for (int e = 0; e < NE; ++e) if (e != i0 && l[e] > m1) { m1 = l[e]; i1 = e; }
    float e1 = expf(m1 - m0);
    float s = 1.f + e1;
    toke[2 * t] = i0;  toke[2 * t + 1] = i1;
    tokw[2 * t] = 1.f / s;  tokw[2 * t + 1] = e1 / s;
    atomicAdd(&ctrl[i0], 1);
    atomicAdd(&ctrl[i1], 1);
  }
}

// exact prefix scan
__global__ void scan_k(int* ctrl) {
  if (threadIdx.x == 0) {
    int off = 0;
    for (int e = 0; e < NE; ++e) {
      ctrl[8 + e] = off;
      ctrl[20 + e] = off;
      off += ctrl[e];
    }
    ctrl[16] = off;
  }
}

__global__ __launch_bounds__(256) void assign_k(
    const int* __restrict__ toke, const float* __restrict__ tokw, int* ctrl,
    int* __restrict__ rowmap, float* __restrict__ wrow, int* __restrict__ rowpos) {
  int t = blockIdx.x * 256 + threadIdx.x;
#pragma unroll
  for (int k = 0; k < 2; ++k) {
    int e = toke[2 * t + k];
    int r = atomicAdd(&ctrl[20 + e], 1);
    rowmap[r] = t;
    wrow[r] = tokw[2 * t + k];
    rowpos[2 * t + k] = r;
  }
}

// ---------------- fp32 -> bf16 transpose convert: src[e][K_][N_] -> dst[e][N_][K_] ----------------
__global__ __launch_bounds__(256) void convT_k(
    const float* __restrict__ src, unsigned short* __restrict__ dst, int K_, int N_) {
  __shared__ unsigned int lds32[64][33];
  int e = blockIdx.z;
  int kb = blockIdx.y << 6, nb = blockIdx.x << 6;
  int t = threadIdx.x;
  const float* s = src + (size_t)e * K_ * N_ + (size_t)kb * N_ + nb;
  int n0 = (t & 15) << 2;
#pragma unroll
  for (int i = 0; i < 2; ++i) {
    int k2 = (i << 4) + (t >> 4);
    float4 a = *(const float4*)(s + (size_t)(2 * k2) * N_ + n0);
    float4 b = *(const float4*)(s + (size_t)(2 * k2 + 1) * N_ + n0);
    lds32[n0 + 0][k2] = (unsigned)f2bf(a.x) | ((unsigned)f2bf(b.x) << 16);
    lds32[n0 + 1][k2] = (unsigned)f2bf(a.y) | ((unsigned)f2bf(b.y) << 16);
    lds32[n0 + 2][k2] = (unsigned)f2bf(a.z) | ((unsigned)f2bf(b.z) << 16);
    lds32[n0 + 3][k2] = (unsigned)f2bf(a.w) | ((unsigned)f2bf(b.w) << 16);
  }
  __syncthreads();
  unsigned short* dp = dst + (size_t)e * (size_t)N_ * K_ + (size_t)nb * K_ + kb;
  int n = t >> 2, c = t & 3;
  uint4 v0, v1;
  v0.x = lds32[n][(c << 2) + 0]; v0.y = lds32[n][(c << 2) + 1];
  v0.z = lds32[n][(c << 2) + 2]; v0.w = lds32[n][(c << 2) + 3];
  int c4 = (c + 4) << 2;
  v1.x = lds32[n][c4 + 0]; v1.y = lds32[n][c4 + 1];
  v1.z = lds32[n][c4 + 2]; v1.w = lds32[n][c4 + 3];
  *(uint4*)(dp + (size_t)n * K_ + (c << 3)) = v0;
  *(uint4*)(dp + (size_t)n * K_ + ((c + 4) << 3)) = v1;
}

// ---------------- grouped expert GEMM: round-2 structure + validated k-chunk swizzle ----------------
// Single 32KiB LDS buffer, stage -> sync -> compute -> sync (5 blocks/CU, cross-block overlap).
// Swizzle (validated r5, conflicts 2.6e7 -> 0): 16B k-chunk index XOR (row>>1)&7, applied to
// global source (involution inverse) and ds_read offset; gload_lds dest stays linear (rule 21).
template <int KTOT, int NTOT, bool GATHER, bool DOGELU, bool KSPLIT2>
__global__ __launch_bounds__(256, 2) void gemm_k(
    const unsigned short* __restrict__ A, const unsigned short* __restrict__ Bt,
    const int* __restrict__ ctrl, const int* __restrict__ rowmap,
    const float* __restrict__ wrow, const float* __restrict__ bias,
    unsigned short* __restrict__ outb, float* __restrict__ outf0, float* __restrict__ outf1) {
  __shared__ __align__(16) unsigned short Asm[128 * 64];
  __shared__ __align__(16) unsigned short Bsm[128 * 64];
  int zz = blockIdx.z;
  int e = KSPLIT2 ? (zz & 7) : zz;
  int ks = KSPLIT2 ? (zz >> 3) : 0;
  int off0 = ctrl[8 + e], off1 = ctrl[8 + e + 1];
  int row0 = off0 + (blockIdx.y << 7);
  if (row0 >= off1) return;
  int col0 = blockIdx.x << 7;
  int tid = threadIdx.x, lane = tid & 63, wid = tid >> 6;
  int wr = wid >> 1, wc = wid & 1;
  int kbeg = KSPLIT2 ? ks * (KTOT / 2) : 0;
  int kend = KSPLIT2 ? kbeg + (KTOT / 2) : KTOT;
  float* outf = (KSPLIT2 && ks) ? outf1 : outf0;

  const unsigned short* Asrc[4];
  const unsigned short* Bsrc[4];
#pragma unroll
  for (int c = 0; c < 4; ++c) {
    int rl = (c << 5) + (tid >> 3);                           // dest row 0..127
    int k0 = (((tid & 7) ^ ((rl >> 1) & 7)) << 3);            // inverse-swizzled source chunk
    int ar = row0 + rl; if (ar > off1 - 1) ar = off1 - 1;
    size_t arow = GATHER ? (size_t)rowmap[ar] : (size_t)ar;
    Asrc[c] = A + arow * KTOT + kbeg + k0;
    Bsrc[c] = Bt + ((size_t)e * NTOT + col0 + rl) * KTOT + kbeg + k0;
  }

  // swizzled fragment offsets (element index into 128x64 tile), [frag][kk-half]
  int offA[4][2], offB[4][2];
#pragma unroll
  for (int m = 0; m < 4; ++m) {
    int r = (wr << 6) + (m << 4) + (lane & 15);
#pragma unroll
    for (int h = 0; h < 2; ++h)
      offA[m][h] = (r << 6) + ((((h << 2) + (lane >> 4)) ^ ((r >> 1) & 7)) << 3);
  }
#pragma unroll
  for (int n = 0; n < 4; ++n) {
    int r = (wc << 6) + (n << 4) + (lane & 15);
#pragma unroll
    for (int h = 0; h < 2; ++h)
      offB[n][h] = (r << 6) + ((((h << 2) + (lane >> 4)) ^ ((r >> 1) & 7)) << 3);
  }

  f32x4 acc[4][4];
#pragma unroll
  for (int m = 0; m < 4; ++m)
#pragma unroll
    for (int n = 0; n < 4; ++n) acc[m][n] = (f32x4){0.f, 0.f, 0.f, 0.f};

  char* AsmB = (char*)Asm;
  char* BsmB = (char*)Bsm;

  for (int k0 = kbeg; k0 < kend; k0 += 64) {
#pragma unroll
    for (int c = 0; c < 4; ++c) {
      async16(AsmB + ((c << 8) + (wid << 6)) * 16, Asrc[c] + (k0 - kbeg));
      async16(BsmB + ((c << 8) + (wid << 6)) * 16, Bsrc[c] + (k0 - kbeg));
    }
    __syncthreads();
#pragma unroll
    for (int h = 0; h < 2; ++h) {
      bf16x8 af[4], bfr[4];
#pragma unroll
      for (int m = 0; m < 4; ++m) af[m] = *(const bf16x8*)&Asm[offA[m][h]];
#pragma unroll
      for (int n = 0; n < 4; ++n) bfr[n] = *(const bf16x8*)&Bsm[offB[n][h]];
#pragma unroll
      for (int m = 0; m < 4; ++m)
#pragma unroll
        for (int n = 0; n < 4; ++n)
          acc[m][n] = __builtin_amdgcn_mfma_f32_16x16x32_bf16(af[m], bfr[n], acc[m][n], 0, 0, 0);
    }
    __syncthreads();
  }

  int r_b = (lane >> 4) << 2;
  int c_b = lane & 15;
  if (DOGELU) {
#pragma unroll
    for (int n = 0; n < 4; ++n) {
      int col = col0 + (wc << 6) + (n << 4) + c_b;
      float bv = bias[e * NTOT + col];
#pragma unroll
      for (int m = 0; m < 4; ++m) {
#pragma unroll
        for (int r = 0; r < 4; ++r) {
          int row = row0 + (wr << 6) + (m << 4) + r_b + r;
          if (row < off1)
            outb[(size_t)row * NTOT + col] = f2bf(gelu_exact(acc[m][n][r] + bv));
        }
      }
    }
  } else {
#pragma unroll
    for (int n = 0; n < 4; ++n) {
      int col = col0 + (wc << 6) + (n << 4) + c_b;
      float bv = (KSPLIT2 && ks) ? 0.f : bias[e * NTOT + col];
#pragma unroll
      for (int m = 0; m < 4; ++m) {
#pragma unroll
        for (int r = 0; r < 4; ++r) {
          int row = row0 + (wr << 6) + (m << 4) + r_b + r;
          if (row < off1)
            outf[(size_t)row * NTOT + col] = wrow[row] * (acc[m][n][r] + bv);
        }
      }
    }
  }
}

// ---------------- gather: weights already baked in; out[t] = p0[r0]+p1[r0]+p0[r1]+p1[r1] ----------------
__global__ __launch_bounds__(256) void gather_k(
    const float* __restrict__ p0, const float* __restrict__ p1,
    const int* __restrict__ rowpos, float* __restrict__ out) {
  int t = blockIdx.x, d = threadIdx.x << 2;
  int r0 = rowpos[2 * t], r1 = rowpos[2 * t + 1];
  float4 a0 = *(const float4*)&p0[(size_t)r0 * DDIM + d];
  float4 a1 = *(const float4*)&p1[(size_t)r0 * DDIM + d];
  float4 b0 = *(const float4*)&p0[(size_t)r1 * DDIM + d];
  float4 b1 = *(const float4*)&p1[(size_t)r1 * DDIM + d];
  float4 o;
  o.x = (a0.x + a1.x) + (b0.x + b1.x);
  o.y = (a0.y + a1.y) + (b0.y + b1.y);
  o.z = (a0.z + a1.z) + (b0.z + b1.z);
  o.w = (a0.w + a1.w) + (b0.w + b1.w);
  *(float4*)&out[(size_t)t * DDIM + d] = o;
}

extern "C" void kernel_launch(void* const* d_in, const int* in_sizes, int n_in,
                              void* d_out, int out_size, void* d_ws, size_t ws_size,
                              hipStream_t stream) {
  const float* x  = (const float*)d_in[0];
  const float* W1 = (const float*)d_in[1];
  const float* b1 = (const float*)d_in[2];
  const float* W2 = (const float*)d_in[3];
  const float* b2 = (const float*)d_in[4];
  const float* Wr = (const float*)d_in[5];
  const float* br = (const float*)d_in[6];
  float* out = (float*)d_out;

  if (ws_size < WS_NEED) return;

  char* ws = (char*)d_ws;
  int* ctrl            = (int*)(ws + OFF_CTRL);
  int* rowmap          = (int*)(ws + OFF_ROWMAP);
  float* wrow          = (float*)(ws + OFF_WROW);
  int* rowpos          = (int*)(ws + OFF_ROWPOS);
  int* toke            = (int*)(ws + OFF_TOKE);
  float* tokw          = (float*)(ws + OFF_TOKW);
  unsigned short* xb   = (unsigned short*)(ws + OFF_XB);
  unsigned short* W1T  = (unsigned short*)(ws + OFF_W1T);
  unsigned short* W2T  = (unsigned short*)(ws + OFF_W2T);
  unsigned short* hbuf = (unsigned short*)(ws + OFF_H);
  float* pout          = (float*)(ws + OFF_PO);
  float* pout2         = (float*)(ws + OFF_W1T);  // aliases W1T — dead after GEMM1

  hipMemsetAsync(ws, 0, 256, stream);  // ctrl only; rowmap/wrow/rowpos fully written

  router_k<<<TT / 4, 256, 0, stream>>>(x, Wr, br, xb, ctrl, toke, tokw);
  scan_k<<<1, 64, 0, stream>>>(ctrl);
  assign_k<<<TT / 256, 256, 0, stream>>>(toke, tokw, ctrl, rowmap, wrow, rowpos);

  convT_k<<<dim3(HDIM / 64, DDIM / 64, NE), 256, 0, stream>>>(W1, W1T, DDIM, HDIM);
  convT_k<<<dim3(DDIM / 64, HDIM / 64, NE), 256, 0, stream>>>(W2, W2T, HDIM, DDIM);

  // GEMM1: h = gelu(x_rows @ W1[e] + b1)   N=4096, K=1024
  gemm_k<DDIM, HDIM, true, true, false><<<dim3(HDIM / 128, 32, NE), 256, 0, stream>>>(
      xb, W1T, ctrl, rowmap, wrow, b1, hbuf, nullptr, nullptr);
  // GEMM2 (K-split 2): pout(+pout2) = w * (h @ W2[e] + b2)   N=1024, K=4096
  gemm_k<HDIM, DDIM, false, false, true><<<dim3(DDIM / 128, 32, NE * 2), 256, 0, stream>>>(
      hbuf, W2T, ctrl, rowmap, wrow, b2, nullptr, pout, pout2);

  gather_k<<<TT, 256, 0, stream>>>(pout, pout2, rowpos, out);
}

// Round 7
// 400.051 us; speedup vs baseline: 3.1736x; 1.2391x over previous
//
#include <hip/hip_runtime.h>
#include <math.h>

typedef __bf16 bf16x8 __attribute__((ext_vector_type(8)));
typedef float f32x4 __attribute__((ext_vector_type(4)));

#define DDIM 1024
#define HDIM 4096
#define NE 8
#define TT 4096
#define CAP 8192

static const size_t OFF_CTRL   = 0;                                      // 256 B (only [8..16] used)
static const size_t OFF_ROWMAP = 256;                                    // CAP*4
static const size_t OFF_WROW   = OFF_ROWMAP + (size_t)CAP * 4;           // CAP*4
static const size_t OFF_ROWPOS = OFF_WROW + (size_t)CAP * 4;             // TT*2*4
static const size_t OFF_TOKE   = OFF_ROWPOS + (size_t)TT * 2 * 4;
static const size_t OFF_TOKW   = OFF_TOKE + (size_t)TT * 2 * 4;
static const size_t OFF_XB     = OFF_TOKW + (size_t)TT * 2 * 4;          // TT*D bf16
static const size_t OFF_W1T    = OFF_XB + (size_t)TT * DDIM * 2;         // E*H*D bf16; reused as pout2 after GEMM1
static const size_t OFF_W2T    = OFF_W1T + (size_t)NE * HDIM * DDIM * 2; // E*D*H bf16
static const size_t OFF_H      = OFF_W2T + (size_t)NE * DDIM * HDIM * 2; // CAP*H bf16
static const size_t OFF_PO     = OFF_H + (size_t)CAP * HDIM * 2;         // CAP*D f32
static const size_t WS_NEED    = OFF_PO + (size_t)CAP * DDIM * 4;

__device__ __forceinline__ unsigned short f2bf(float f) {
  unsigned int u = __builtin_bit_cast(unsigned int, f);
  u = (u + 0x7FFFu + ((u >> 16) & 1u)) >> 16;
  return (unsigned short)u;
}

__device__ __forceinline__ void async16(void* lds, const void* g) {
  __builtin_amdgcn_global_load_lds(
      (__attribute__((address_space(1))) void*)g,
      (__attribute__((address_space(3))) void*)lds, 16, 0, 0);
}

__device__ __forceinline__ float gelu_exact(float v) {
  return 0.5f * v * (1.0f + erff(v * 0.70710678118654752f));
}

// ---------------- router: logits, top-2, weights; x -> bf16. NO atomics. ----------------
__global__ __launch_bounds__(256) void router_k(
    const float* __restrict__ x, const float* __restrict__ Wr, const float* __restrict__ br,
    unsigned short* __restrict__ xb, int* __restrict__ toke, float* __restrict__ tokw) {
  int tid = threadIdx.x, lane = tid & 63, wid = tid >> 6;
  int t = blockIdx.x * 4 + wid;
  const float* xr = x + (size_t)t * DDIM;
  float acc[NE];
#pragma unroll
  for (int e = 0; e < NE; ++e) acc[e] = 0.f;
#pragma unroll
  for (int it = 0; it < DDIM / 64; ++it) {
    int d = lane + it * 64;
    float xv = xr[d];
    xb[(size_t)t * DDIM + d] = f2bf(xv);
    const float4* w4 = (const float4*)(Wr + (size_t)d * NE);
    float4 wa = w4[0], wb = w4[1];
    acc[0] += xv * wa.x; acc[1] += xv * wa.y; acc[2] += xv * wa.z; acc[3] += xv * wa.w;
    acc[4] += xv * wb.x; acc[5] += xv * wb.y; acc[6] += xv * wb.z; acc[7] += xv * wb.w;
  }
#pragma unroll
  for (int e = 0; e < NE; ++e) {
#pragma unroll
    for (int s = 32; s > 0; s >>= 1) acc[e] += __shfl_xor(acc[e], s, 64);
  }
  if (lane == 0) {
    float l[NE];
#pragma unroll
    for (int e = 0; e < NE; ++e) l[e] = acc[e] + br[e];
    int i0 = 0; float m0 = l[0];
#pragma unroll
    for (int e = 1; e < NE; ++e) if (l[e] > m0) { m0 = l[e]; i0 = e; }
    int i1 = -1; float m1 = -3.4e38f;
#pragma unroll
    for (int e = 0; e < NE; ++e) if (e != i0 && l[e] > m1) { m1 = l[e]; i1 = e; }
    float e1 = expf(m1 - m0);
    float s = 1.f + e1;
    toke[2 * t] = i0;  toke[2 * t + 1] = i1;
    tokw[2 * t] = 1.f / s;  tokw[2 * t + 1] = e1 / s;
  }
}

// ---------------- deterministic ballot binning: one block, zero atomics ----------------
// Slot s in [0, 8192): token s>>1, choice s&1. Stable order = slot order.
__global__ __launch_bounds__(1024) void bin_k(
    const int* __restrict__ toke, const float* __restrict__ tokw,
    int* __restrict__ ctrl, int* __restrict__ rowmap,
    float* __restrict__ wrow, int* __restrict__ rowpos) {
  __shared__ int wcnt[16][8];
  __shared__ int wpre[16][8];
  __shared__ int ebase[8];
  int tid = threadIdx.x, lane = tid & 63, w = tid >> 6;

  // pass 1: per-expert totals
  int myCnt = 0;  // lane<8: this wave's count of expert 'lane'
  for (int c = 0; c < 8; ++c) {
    int e = toke[c * 1024 + tid];
#pragma unroll
    for (int ee = 0; ee < 8; ++ee) {
      unsigned long long m = __ballot(e == ee);
      if (lane == ee) myCnt += (int)__popcll(m);
    }
  }
  if (lane < 8) wcnt[w][lane] = myCnt;
  __syncthreads();
  if (tid == 0) {
    int off = 0;
    for (int e = 0; e < 8; ++e) {
      int s = 0;
      for (int ww = 0; ww < 16; ++ww) s += wcnt[ww][e];
      ctrl[8 + e] = off;
      ebase[e] = off;
      off += s;
    }
    ctrl[16] = off;
  }
  __syncthreads();

  // pass 2: stable placement
  for (int c = 0; c < 8; ++c) {
    int slot = c * 1024 + tid;
    int e = toke[slot];
    unsigned long long mown = 0;
#pragma unroll
    for (int ee = 0; ee < 8; ++ee) {
      unsigned long long m = __ballot(e == ee);
      if (lane == ee) wcnt[w][ee] = (int)__popcll(m);
      if (e == ee) mown = m;
    }
    __syncthreads();
    if (tid < 128) {
      int ww = tid >> 3, ee = tid & 7;
      int s = 0;
      for (int p = 0; p < ww; ++p) s += wcnt[p][ee];
      wpre[ww][ee] = s;
    }
    __syncthreads();
    int rank = (int)__popcll(mown & ((1ull << lane) - 1ull));
    int r = ebase[e] + wpre[w][e] + rank;
    rowmap[r] = slot >> 1;
    wrow[r] = tokw[slot];
    rowpos[slot] = r;
    __syncthreads();
    if (tid < 8) {
      int s = 0;
      for (int ww = 0; ww < 16; ++ww) s += wcnt[ww][tid];
      ebase[tid] += s;
    }
    __syncthreads();
  }
}

// ---------------- fp32 -> bf16 transpose convert: src[e][K_][N_] -> dst[e][N_][K_] ----------------
__global__ __launch_bounds__(256) void convT_k(
    const float* __restrict__ src, unsigned short* __restrict__ dst, int K_, int N_) {
  __shared__ unsigned int lds32[64][33];
  int e = blockIdx.z;
  int kb = blockIdx.y << 6, nb = blockIdx.x << 6;
  int t = threadIdx.x;
  const float* s = src + (size_t)e * K_ * N_ + (size_t)kb * N_ + nb;
  int n0 = (t & 15) << 2;
#pragma unroll
  for (int i = 0; i < 2; ++i) {
    int k2 = (i << 4) + (t >> 4);
    float4 a = *(const float4*)(s + (size_t)(2 * k2) * N_ + n0);
    float4 b = *(const float4*)(s + (size_t)(2 * k2 + 1) * N_ + n0);
    lds32[n0 + 0][k2] = (unsigned)f2bf(a.x) | ((unsigned)f2bf(b.x) << 16);
    lds32[n0 + 1][k2] = (unsigned)f2bf(a.y) | ((unsigned)f2bf(b.y) << 16);
    lds32[n0 + 2][k2] = (unsigned)f2bf(a.z) | ((unsigned)f2bf(b.z) << 16);
    lds32[n0 + 3][k2] = (unsigned)f2bf(a.w) | ((unsigned)f2bf(b.w) << 16);
  }
  __syncthreads();
  unsigned short* dp = dst + (size_t)e * (size_t)N_ * K_ + (size_t)nb * K_ + kb;
  int n = t >> 2, c = t & 3;
  uint4 v0, v1;
  v0.x = lds32[n][(c << 2) + 0]; v0.y = lds32[n][(c << 2) + 1];
  v0.z = lds32[n][(c << 2) + 2]; v0.w = lds32[n][(c << 2) + 3];
  int c4 = (c + 4) << 2;
  v1.x = lds32[n][c4 + 0]; v1.y = lds32[n][c4 + 1];
  v1.z = lds32[n][c4 + 2]; v1.w = lds32[n][c4 + 3];
  *(uint4*)(dp + (size_t)n * K_ + (c << 3)) = v0;
  *(uint4*)(dp + (size_t)n * K_ + ((c + 4) << 3)) = v1;
}

// ---------------- grouped expert GEMM: round-2 proven structure (unswizzled) ----------------
template <int KTOT, int NTOT, bool GATHER, bool DOGELU, bool KSPLIT2>
__global__ __launch_bounds__(256, 2) void gemm_k(
    const unsigned short* __restrict__ A, const unsigned short* __restrict__ Bt,
    const int* __restrict__ ctrl, const int* __restrict__ rowmap,
    const float* __restrict__ wrow, const float* __restrict__ bias,
    unsigned short* __restrict__ outb, float* __restrict__ outf0, float* __restrict__ outf1) {
  __shared__ __align__(16) unsigned short Asm[128 * 64];
  __shared__ __align__(16) unsigned short Bsm[128 * 64];
  int zz = blockIdx.z;
  int e = KSPLIT2 ? (zz & 7) : zz;
  int ks = KSPLIT2 ? (zz >> 3) : 0;
  int off0 = ctrl[8 + e], off1 = ctrl[8 + e + 1];
  int row0 = off0 + (blockIdx.y << 7);
  if (row0 >= off1) return;
  int col0 = blockIdx.x << 7;
  int tid = threadIdx.x, lane = tid & 63, wid = tid >> 6;
  int wr = wid >> 1, wc = wid & 1;
  int kbeg = KSPLIT2 ? ks * (KTOT / 2) : 0;
  int kend = KSPLIT2 ? kbeg + (KTOT / 2) : KTOT;
  float* outf = (KSPLIT2 && ks) ? outf1 : outf0;

  const unsigned short* Asrc[4];
  const unsigned short* Bsrc[4];
#pragma unroll
  for (int c = 0; c < 4; ++c) {
    int rl = (c << 5) + (tid >> 3);
    int ar = row0 + rl; if (ar > off1 - 1) ar = off1 - 1;
    size_t arow = GATHER ? (size_t)rowmap[ar] : (size_t)ar;
    Asrc[c] = A + arow * KTOT + ((tid & 7) << 3);
    Bsrc[c] = Bt + ((size_t)e * NTOT + col0 + rl) * KTOT + ((tid & 7) << 3);
  }

  f32x4 acc[4][4];
#pragma unroll
  for (int m = 0; m < 4; ++m)
#pragma unroll
    for (int n = 0; n < 4; ++n) acc[m][n] = (f32x4){0.f, 0.f, 0.f, 0.f};

  int arow_rd = ((wr << 6) + (lane & 15)) << 6;
  int brow_rd = ((wc << 6) + (lane & 15)) << 6;
  int koff = (lane >> 4) << 3;
  char* AsmB = (char*)Asm;
  char* BsmB = (char*)Bsm;

  for (int k0 = kbeg; k0 < kend; k0 += 64) {
#pragma unroll
    for (int c = 0; c < 4; ++c) {
      async16(AsmB + ((c << 8) + (wid << 6)) * 16, Asrc[c] + k0);
      async16(BsmB + ((c << 8) + (wid << 6)) * 16, Bsrc[c] + k0);
    }
    __syncthreads();
#pragma unroll
    for (int kk = 0; kk < 64; kk += 32) {
      bf16x8 af[4], bfr[4];
#pragma unroll
      for (int m = 0; m < 4; ++m)
        af[m] = *(const bf16x8*)&Asm[arow_rd + (m << 10) + kk + koff];
#pragma unroll
      for (int n = 0; n < 4; ++n)
        bfr[n] = *(const bf16x8*)&Bsm[brow_rd + (n << 10) + kk + koff];
#pragma unroll
      for (int m = 0; m < 4; ++m)
#pragma unroll
        for (int n = 0; n < 4; ++n)
          acc[m][n] = __builtin_amdgcn_mfma_f32_16x16x32_bf16(af[m], bfr[n], acc[m][n], 0, 0, 0);
    }
    __syncthreads();
  }

  int r_b = (lane >> 4) << 2;
  int c_b = lane & 15;
  if (DOGELU) {
#pragma unroll
    for (int n = 0; n < 4; ++n) {
      int col = col0 + (wc << 6) + (n << 4) + c_b;
      float bv = bias[e * NTOT + col];
#pragma unroll
      for (int m = 0; m < 4; ++m) {
#pragma unroll
        for (int r = 0; r < 4; ++r) {
          int row = row0 + (wr << 6) + (m << 4) + r_b + r;
          if (row < off1)
            outb[(size_t)row * NTOT + col] = f2bf(gelu_exact(acc[m][n][r] + bv));
        }
      }
    }
  } else {
#pragma unroll
    for (int n = 0; n < 4; ++n) {
      int col = col0 + (wc << 6) + (n << 4) + c_b;
      float bv = (KSPLIT2 && ks) ? 0.f : bias[e * NTOT + col];
#pragma unroll
      for (int m = 0; m < 4; ++m) {
#pragma unroll
        for (int r = 0; r < 4; ++r) {
          int row = row0 + (wr << 6) + (m << 4) + r_b + r;
          if (row < off1)
            outf[(size_t)row * NTOT + col] = wrow[row] * (acc[m][n][r] + bv);
        }
      }
    }
  }
}

// ---------------- gather: weights pre-applied; out[t] = p0[r0]+p1[r0]+p0[r1]+p1[r1] ----------------
__global__ __launch_bounds__(256) void gather_k(
    const float* __restrict__ p0, const float* __restrict__ p1,
    const int* __restrict__ rowpos, float* __restrict__ out) {
  int t = blockIdx.x, d = threadIdx.x << 2;
  int r0 = rowpos[2 * t], r1 = rowpos[2 * t + 1];
  float4 a0 = *(const float4*)&p0[(size_t)r0 * DDIM + d];
  float4 a1 = *(const float4*)&p1[(size_t)r0 * DDIM + d];
  float4 b0 = *(const float4*)&p0[(size_t)r1 * DDIM + d];
  float4 b1 = *(const float4*)&p1[(size_t)r1 * DDIM + d];
  float4 o;
  o.x = (a0.x + a1.x) + (b0.x + b1.x);
  o.y = (a0.y + a1.y) + (b0.y + b1.y);
  o.z = (a0.z + a1.z) + (b0.z + b1.z);
  o.w = (a0.w + a1.w) + (b0.w + b1.w);
  *(float4*)&out[(size_t)t * DDIM + d] = o;
}

extern "C" void kernel_launch(void* const* d_in, const int* in_sizes, int n_in,
                              void* d_out, int out_size, void* d_ws, size_t ws_size,
                              hipStream_t stream) {
  const float* x  = (const float*)d_in[0];
  const float* W1 = (const float*)d_in[1];
  const float* b1 = (const float*)d_in[2];
  const float* W2 = (const float*)d_in[3];
  const float* b2 = (const float*)d_in[4];
  const float* Wr = (const float*)d_in[5];
  const float* br = (const float*)d_in[6];
  float* out = (float*)d_out;

  if (ws_size < WS_NEED) return;

  char* ws = (char*)d_ws;
  int* ctrl            = (int*)(ws + OFF_CTRL);
  int* rowmap          = (int*)(ws + OFF_ROWMAP);
  float* wrow          = (float*)(ws + OFF_WROW);
  int* rowpos          = (int*)(ws + OFF_ROWPOS);
  int* toke            = (int*)(ws + OFF_TOKE);
  float* tokw          = (float*)(ws + OFF_TOKW);
  unsigned short* xb   = (unsigned short*)(ws + OFF_XB);
  unsigned short* W1T  = (unsigned short*)(ws + OFF_W1T);
  unsigned short* W2T  = (unsigned short*)(ws + OFF_W2T);
  unsigned short* hbuf = (unsigned short*)(ws + OFF_H);
  float* pout          = (float*)(ws + OFF_PO);
  float* pout2         = (float*)(ws + OFF_W1T);  // aliases W1T — dead after GEMM1

  router_k<<<TT / 4, 256, 0, stream>>>(x, Wr, br, xb, toke, tokw);
  bin_k<<<1, 1024, 0, stream>>>(toke, tokw, ctrl, rowmap, wrow, rowpos);

  convT_k<<<dim3(HDIM / 64, DDIM / 64, NE), 256, 0, stream>>>(W1, W1T, DDIM, HDIM);
  convT_k<<<dim3(DDIM / 64, HDIM / 64, NE), 256, 0, stream>>>(W2, W2T, HDIM, DDIM);

  // GEMM1: h = gelu(x_rows @ W1[e] + b1)   N=4096, K=1024
  gemm_k<DDIM, HDIM, true, true, false><<<dim3(HDIM / 128, 32, NE), 256, 0, stream>>>(
      xb, W1T, ctrl, rowmap, wrow, b1, hbuf, nullptr, nullptr);
  // GEMM2 (K-split 2): pout(+pout2) = w * (h @ W2[e] + b2)   N=1024, K=4096
  gemm_k<HDIM, DDIM, false, false, true><<<dim3(DDIM / 128, 32, NE * 2), 256, 0, stream>>>(
      hbuf, W2T, ctrl, rowmap, wrow, b2, nullptr, pout, pout2);

  gather_k<<<TT, 256, 0, stream>>>(pout, pout2, rowpos, out);
}

// Round 8
// 377.704 us; speedup vs baseline: 3.3614x; 1.0592x over previous
//
#include <hip/hip_runtime.h>
#include <math.h>

typedef __bf16 bf16x8 __attribute__((ext_vector_type(8)));
typedef float f32x4 __attribute__((ext_vector_type(4)));

#define DDIM 1024
#define HDIM 4096
#define NE 8
#define TT 4096
#define CAP 9216   // 8192 + 8*128 padding headroom

static const size_t OFF_CTRL   = 0;                                      // 256 B (ctrl[8..16] = padded offsets)
static const size_t OFF_ROWMAP = 256;                                    // CAP*4
static const size_t OFF_WROW   = OFF_ROWMAP + (size_t)CAP * 4;           // CAP*4
static const size_t OFF_ROWPOS = OFF_WROW + (size_t)CAP * 4;             // TT*2*4
static const size_t OFF_TOKE   = OFF_ROWPOS + (size_t)TT * 2 * 4;
static const size_t OFF_TOKW   = OFF_TOKE + (size_t)TT * 2 * 4;
static const size_t OFF_XB     = OFF_TOKW + (size_t)TT * 2 * 4;          // TT*D bf16
static const size_t OFF_W1T    = OFF_XB + (size_t)TT * DDIM * 2;         // E*H*D bf16; reused as pout2 after GEMM1
static const size_t OFF_W2T    = OFF_W1T + (size_t)NE * HDIM * DDIM * 2; // E*D*H bf16
static const size_t OFF_H      = OFF_W2T + (size_t)NE * DDIM * HDIM * 2; // CAP*H bf16
static const size_t OFF_PO     = OFF_H + (size_t)CAP * HDIM * 2;         // CAP*D f32
static const size_t WS_NEED    = OFF_PO + (size_t)CAP * DDIM * 4;        // ~244 MiB (proven in r1)

__device__ __forceinline__ unsigned short f2bf(float f) {
  unsigned int u = __builtin_bit_cast(unsigned int, f);
  u = (u + 0x7FFFu + ((u >> 16) & 1u)) >> 16;
  return (unsigned short)u;
}

__device__ __forceinline__ void async16(void* lds, const void* g) {
  __builtin_amdgcn_global_load_lds(
      (__attribute__((address_space(1))) void*)g,
      (__attribute__((address_space(3))) void*)lds, 16, 0, 0);
}

__device__ __forceinline__ float gelu_exact(float v) {
  return 0.5f * v * (1.0f + erff(v * 0.70710678118654752f));
}

// ---------------- router: logits, top-2, weights; x -> bf16. NO atomics. ----------------
__global__ __launch_bounds__(256) void router_k(
    const float* __restrict__ x, const float* __restrict__ Wr, const float* __restrict__ br,
    unsigned short* __restrict__ xb, int* __restrict__ toke, float* __restrict__ tokw) {
  int tid = threadIdx.x, lane = tid & 63, wid = tid >> 6;
  int t = blockIdx.x * 4 + wid;
  const float* xr = x + (size_t)t * DDIM;
  float acc[NE];
#pragma unroll
  for (int e = 0; e < NE; ++e) acc[e] = 0.f;
#pragma unroll
  for (int it = 0; it < DDIM / 64; ++it) {
    int d = lane + it * 64;
    float xv = xr[d];
    xb[(size_t)t * DDIM + d] = f2bf(xv);
    const float4* w4 = (const float4*)(Wr + (size_t)d * NE);
    float4 wa = w4[0], wb = w4[1];
    acc[0] += xv * wa.x; acc[1] += xv * wa.y; acc[2] += xv * wa.z; acc[3] += xv * wa.w;
    acc[4] += xv * wb.x; acc[5] += xv * wb.y; acc[6] += xv * wb.z; acc[7] += xv * wb.w;
  }
#pragma unroll
  for (int e = 0; e < NE; ++e) {
#pragma unroll
    for (int s = 32; s > 0; s >>= 1) acc[e] += __shfl_xor(acc[e], s, 64);
  }
  if (lane == 0) {
    float l[NE];
#pragma unroll
    for (int e = 0; e < NE; ++e) l[e] = acc[e] + br[e];
    int i0 = 0; float m0 = l[0];
#pragma unroll
    for (int e = 1; e < NE; ++e) if (l[e] > m0) { m0 = l[e]; i0 = e; }
    int i1 = -1; float m1 = -3.4e38f;
#pragma unroll
    for (int e = 0; e < NE; ++e) if (e != i0 && l[e] > m1) { m1 = l[e]; i1 = e; }
    float e1 = expf(m1 - m0);
    float s = 1.f + e1;
    toke[2 * t] = i0;  toke[2 * t + 1] = i1;
    tokw[2 * t] = 1.f / s;  tokw[2 * t + 1] = e1 / s;
  }
}

// ---------------- deterministic ballot binning + 128-padding: one block, zero atomics ----------------
// Slot s in [0, 8192): token s>>1, choice s&1. Stable order = slot order.
// Expert bases are 128-aligned; pad rows get rowmap=0, wrow=0 (harmless, never gathered).
__global__ __launch_bounds__(1024) void bin_k(
    const int* __restrict__ toke, const float* __restrict__ tokw,
    int* __restrict__ ctrl, int* __restrict__ rowmap,
    float* __restrict__ wrow, int* __restrict__ rowpos) {
  __shared__ int wcnt[16][8];
  __shared__ int wpre[16][8];
  __shared__ int pbase[9];   // padded bases (const after pass 1)
  __shared__ int ecnt[8];    // exact counts
  __shared__ int ebase[8];   // running cursor for pass 2
  int tid = threadIdx.x, lane = tid & 63, w = tid >> 6;

  // pass 1: per-expert totals
  int myCnt = 0;
  for (int c = 0; c < 8; ++c) {
    int e = toke[c * 1024 + tid];
#pragma unroll
    for (int ee = 0; ee < 8; ++ee) {
      unsigned long long m = __ballot(e == ee);
      if (lane == ee) myCnt += (int)__popcll(m);
    }
  }
  if (lane < 8) wcnt[w][lane] = myCnt;
  __syncthreads();
  if (tid == 0) {
    int off = 0;
    for (int e = 0; e < 8; ++e) {
      int s = 0;
      for (int ww = 0; ww < 16; ++ww) s += wcnt[ww][e];
      ecnt[e] = s;
      pbase[e] = off;
      ebase[e] = off;
      ctrl[8 + e] = off;
      off += ((s + 127) >> 7) << 7;
    }
    pbase[8] = off;
    ctrl[16] = off;
  }
  __syncthreads();

  // zero-fill pad region
  for (int e = 0; e < 8; ++e) {
    int start = pbase[e] + ecnt[e], end = pbase[e + 1];
    for (int r = start + tid; r < end; r += 1024) { rowmap[r] = 0; wrow[r] = 0.f; }
  }

  // pass 2: stable placement from padded bases
  for (int c = 0; c < 8; ++c) {
    int slot = c * 1024 + tid;
    int e = toke[slot];
    unsigned long long mown = 0;
#pragma unroll
    for (int ee = 0; ee < 8; ++ee) {
      unsigned long long m = __ballot(e == ee);
      if (lane == ee) wcnt[w][ee] = (int)__popcll(m);
      if (e == ee) mown = m;
    }
    __syncthreads();
    if (tid < 128) {
      int ww = tid >> 3, ee = tid & 7;
      int s = 0;
      for (int p = 0; p < ww; ++p) s += wcnt[p][ee];
      wpre[ww][ee] = s;
    }
    __syncthreads();
    int rank = (int)__popcll(mown & ((1ull << lane) - 1ull));
    int r = ebase[e] + wpre[w][e] + rank;
    rowmap[r] = slot >> 1;
    wrow[r] = tokw[slot];
    rowpos[slot] = r;
    __syncthreads();
    if (tid < 8) {
      int s = 0;
      for (int ww = 0; ww < 16; ++ww) s += wcnt[ww][tid];
      ebase[tid] += s;
    }
    __syncthreads();
  }
}

// ---------------- fp32 -> bf16 transpose convert: src[e][K_][N_] -> dst[e][N_][K_] ----------------
__global__ __launch_bounds__(256) void convT_k(
    const float* __restrict__ src, unsigned short* __restrict__ dst, int K_, int N_) {
  __shared__ unsigned int lds32[64][33];
  int e = blockIdx.z;
  int kb = blockIdx.y << 6, nb = blockIdx.x << 6;
  int t = threadIdx.x;
  const float* s = src + (size_t)e * K_ * N_ + (size_t)kb * N_ + nb;
  int n0 = (t & 15) << 2;
#pragma unroll
  for (int i = 0; i < 2; ++i) {
    int k2 = (i << 4) + (t >> 4);
    float4 a = *(const float4*)(s + (size_t)(2 * k2) * N_ + n0);
    float4 b = *(const float4*)(s + (size_t)(2 * k2 + 1) * N_ + n0);
    lds32[n0 + 0][k2] = (unsigned)f2bf(a.x) | ((unsigned)f2bf(b.x) << 16);
    lds32[n0 + 1][k2] = (unsigned)f2bf(a.y) | ((unsigned)f2bf(b.y) << 16);
    lds32[n0 + 2][k2] = (unsigned)f2bf(a.z) | ((unsigned)f2bf(b.z) << 16);
    lds32[n0 + 3][k2] = (unsigned)f2bf(a.w) | ((unsigned)f2bf(b.w) << 16);
  }
  __syncthreads();
  unsigned short* dp = dst + (size_t)e * (size_t)N_ * K_ + (size_t)nb * K_ + kb;
  int n = t >> 2, c = t & 3;
  uint4 v0, v1;
  v0.x = lds32[n][(c << 2) + 0]; v0.y = lds32[n][(c << 2) + 1];
  v0.z = lds32[n][(c << 2) + 2]; v0.w = lds32[n][(c << 2) + 3];
  int c4 = (c + 4) << 2;
  v1.x = lds32[n][c4 + 0]; v1.y = lds32[n][c4 + 1];
  v1.z = lds32[n][c4 + 2]; v1.w = lds32[n][c4 + 3];
  *(uint4*)(dp + (size_t)n * K_ + (c << 3)) = v0;
  *(uint4*)(dp + (size_t)n * K_ + ((c + 4) << 3)) = v1;
}

// ---------------- grouped expert GEMM: round-2 proven structure, padded (no guards) ----------------
template <int KTOT, int NTOT, bool GATHER, bool DOGELU, bool KSPLIT2>
__global__ __launch_bounds__(256, 2) void gemm_k(
    const unsigned short* __restrict__ A, const unsigned short* __restrict__ Bt,
    const int* __restrict__ ctrl, const int* __restrict__ rowmap,
    const float* __restrict__ wrow, const float* __restrict__ bias,
    unsigned short* __restrict__ outb, float* __restrict__ outf0, float* __restrict__ outf1) {
  __shared__ __align__(16) unsigned short Asm[128 * 64];
  __shared__ __align__(16) unsigned short Bsm[128 * 64];
  int zz = blockIdx.z;
  int e = KSPLIT2 ? (zz & 7) : zz;
  int ks = KSPLIT2 ? (zz >> 3) : 0;
  int off0 = ctrl[8 + e], off1 = ctrl[8 + e + 1];
  int row0 = off0 + (blockIdx.y << 7);
  if (row0 >= off1) return;
  int col0 = blockIdx.x << 7;
  int tid = threadIdx.x, lane = tid & 63, wid = tid >> 6;
  int wr = wid >> 1, wc = wid & 1;
  int kbeg = KSPLIT2 ? ks * (KTOT / 2) : 0;
  int kend = KSPLIT2 ? kbeg + (KTOT / 2) : KTOT;
  float* outf = (KSPLIT2 && ks) ? outf1 : outf0;

  const unsigned short* Asrc[4];
  const unsigned short* Bsrc[4];
#pragma unroll
  for (int c = 0; c < 4; ++c) {
    int ar = row0 + (c << 5) + (tid >> 3);
    size_t arow = GATHER ? (size_t)rowmap[ar] : (size_t)ar;
    Asrc[c] = A + arow * KTOT + ((tid & 7) << 3);
    int brw = col0 + (c << 5) + (tid >> 3);
    Bsrc[c] = Bt + ((size_t)e * NTOT + brw) * KTOT + ((tid & 7) << 3);
  }

  f32x4 acc[4][4];
#pragma unroll
  for (int m = 0; m < 4; ++m)
#pragma unroll
    for (int n = 0; n < 4; ++n) acc[m][n] = (f32x4){0.f, 0.f, 0.f, 0.f};

  int arow_rd = ((wr << 6) + (lane & 15)) << 6;
  int brow_rd = ((wc << 6) + (lane & 15)) << 6;
  int koff = (lane >> 4) << 3;
  char* AsmB = (char*)Asm;
  char* BsmB = (char*)Bsm;

  for (int k0 = kbeg; k0 < kend; k0 += 64) {
#pragma unroll
    for (int c = 0; c < 4; ++c) {
      async16(AsmB + ((c << 8) + (wid << 6)) * 16, Asrc[c] + k0);
      async16(BsmB + ((c << 8) + (wid << 6)) * 16, Bsrc[c] + k0);
    }
    __syncthreads();
#pragma unroll
    for (int kk = 0; kk < 64; kk += 32) {
      bf16x8 af[4], bfr[4];
#pragma unroll
      for (int m = 0; m < 4; ++m)
        af[m] = *(const bf16x8*)&Asm[arow_rd + (m << 10) + kk + koff];
#pragma unroll
      for (int n = 0; n < 4; ++n)
        bfr[n] = *(const bf16x8*)&Bsm[brow_rd + (n << 10) + kk + koff];
#pragma unroll
      for (int m = 0; m < 4; ++m)
#pragma unroll
        for (int n = 0; n < 4; ++n)
          acc[m][n] = __builtin_amdgcn_mfma_f32_16x16x32_bf16(af[m], bfr[n], acc[m][n], 0, 0, 0);
    }
    __syncthreads();
  }

  int r_b = (lane >> 4) << 2;
  int c_b = lane & 15;
  if (DOGELU) {
#pragma unroll
    for (int n = 0; n < 4; ++n) {
      int col = col0 + (wc << 6) + (n << 4) + c_b;
      float bv = bias[e * NTOT + col];
#pragma unroll
      for (int m = 0; m < 4; ++m) {
#pragma unroll
        for (int r = 0; r < 4; ++r) {
          int row = row0 + (wr << 6) + (m << 4) + r_b + r;
          outb[(size_t)row * NTOT + col] = f2bf(gelu_exact(acc[m][n][r] + bv));
        }
      }
    }
  } else {
#pragma unroll
    for (int n = 0; n < 4; ++n) {
      int col = col0 + (wc << 6) + (n << 4) + c_b;
      float bv = (KSPLIT2 && ks) ? 0.f : bias[e * NTOT + col];
#pragma unroll
      for (int m = 0; m < 4; ++m) {
#pragma unroll
        for (int r = 0; r < 4; ++r) {
          int row = row0 + (wr << 6) + (m << 4) + r_b + r;
          outf[(size_t)row * NTOT + col] = wrow[row] * (acc[m][n][r] + bv);
        }
      }
    }
  }
}

// ---------------- gather: weights pre-applied; out[t] = p0[r0]+p1[r0]+p0[r1]+p1[r1] ----------------
__global__ __launch_bounds__(256) void gather_k(
    const float* __restrict__ p0, const float* __restrict__ p1,
    const int* __restrict__ rowpos, float* __restrict__ out) {
  int t = blockIdx.x, d = threadIdx.x << 2;
  int r0 = rowpos[2 * t], r1 = rowpos[2 * t + 1];
  float4 a0 = *(const float4*)&p0[(size_t)r0 * DDIM + d];
  float4 a1 = *(const float4*)&p1[(size_t)r0 * DDIM + d];
  float4 b0 = *(const float4*)&p0[(size_t)r1 * DDIM + d];
  float4 b1 = *(const float4*)&p1[(size_t)r1 * DDIM + d];
  float4 o;
  o.x = (a0.x + a1.x) + (b0.x + b1.x);
  o.y = (a0.y + a1.y) + (b0.y + b1.y);
  o.z = (a0.z + a1.z) + (b0.z + b1.z);
  o.w = (a0.w + a1.w) + (b0.w + b1.w);
  *(float4*)&out[(size_t)t * DDIM + d] = o;
}

extern "C" void kernel_launch(void* const* d_in, const int* in_sizes, int n_in,
                              void* d_out, int out_size, void* d_ws, size_t ws_size,
                              hipStream_t stream) {
  const float* x  = (const float*)d_in[0];
  const float* W1 = (const float*)d_in[1];
  const float* b1 = (const float*)d_in[2];
  const float* W2 = (const float*)d_in[3];
  const float* b2 = (const float*)d_in[4];
  const float* Wr = (const float*)d_in[5];
  const float* br = (const float*)d_in[6];
  float* out = (float*)d_out;

  if (ws_size < WS_NEED) return;

  char* ws = (char*)d_ws;
  int* ctrl            = (int*)(ws + OFF_CTRL);
  int* rowmap          = (int*)(ws + OFF_ROWMAP);
  float* wrow          = (float*)(ws + OFF_WROW);
  int* rowpos          = (int*)(ws + OFF_ROWPOS);
  int* toke            = (int*)(ws + OFF_TOKE);
  float* tokw          = (float*)(ws + OFF_TOKW);
  unsigned short* xb   = (unsigned short*)(ws + OFF_XB);
  unsigned short* W1T  = (unsigned short*)(ws + OFF_W1T);
  unsigned short* W2T  = (unsigned short*)(ws + OFF_W2T);
  unsigned short* hbuf = (unsigned short*)(ws + OFF_H);
  float* pout          = (float*)(ws + OFF_PO);
  float* pout2         = (float*)(ws + OFF_W1T);  // aliases W1T — dead after GEMM1

  router_k<<<TT / 4, 256, 0, stream>>>(x, Wr, br, xb, toke, tokw);
  bin_k<<<1, 1024, 0, stream>>>(toke, tokw, ctrl, rowmap, wrow, rowpos);

  convT_k<<<dim3(HDIM / 64, DDIM / 64, NE), 256, 0, stream>>>(W1, W1T, DDIM, HDIM);
  convT_k<<<dim3(DDIM / 64, HDIM / 64, NE), 256, 0, stream>>>(W2, W2T, HDIM, DDIM);

  // GEMM1: h = gelu(x_rows @ W1[e] + b1)   N=4096, K=1024
  gemm_k<DDIM, HDIM, true, true, false><<<dim3(HDIM / 128, 32, NE), 256, 0, stream>>>(
      xb, W1T, ctrl, rowmap, wrow, b1, hbuf, nullptr, nullptr);
  // GEMM2 (K-split 2): pout(+pout2) = w * (h @ W2[e] + b2)   N=1024, K=4096
  gemm_k<HDIM, DDIM, false, false, true><<<dim3(DDIM / 128, 32, NE * 2), 256, 0, stream>>>(
      hbuf, W2T, ctrl, rowmap, wrow, b2, nullptr, pout, pout2);

  gather_k<<<TT, 256, 0, stream>>>(pout, pout2, rowpos, out);
}